// Round 16
// baseline (295.731 us; speedup 1.0000x reference)
//
#include <hip/hip_runtime.h>
#include <hip/hip_bf16.h>
#include <cstdint>
#include <cstddef>

// ---- problem constants ----
constexpr int LQc = 1024, LKc = 1024, Bc = 8, Ec = 1024, Hc = 16, Dc = 64;

typedef __bf16 bf16;
typedef __bf16 bf16x4 __attribute__((ext_vector_type(4)));
typedef __bf16 bf16x8 __attribute__((ext_vector_type(8)));
typedef float  f32x4  __attribute__((ext_vector_type(4)));

#define MFMA16(a, b, c) __builtin_amdgcn_mfma_f32_16x16x32_bf16((a), (b), (c), 0, 0, 0)
#define EXP2F(x) __builtin_amdgcn_exp2f(x)   // v_exp_f32: D = 2^S0 (native)

__device__ __forceinline__ void gload_lds16(const bf16* g, bf16* l) {
  __builtin_amdgcn_global_load_lds((const __attribute__((address_space(1))) void*)g,
                                   (__attribute__((address_space(3))) void*)l, 16, 0, 0);
}

// ============================================================================
// Convert f32 inputs -> bf16, concatenated into ws. query scaled by
// 0.125 * log2(e) = 0.1803369 (folds attention scaling AND the exp->exp2
// base change into the Q projection; softmax normalization cancels the base).
// ============================================================================
__global__ __launch_bounds__(256) void k_convert(const float* __restrict__ q,
                                                 const float* __restrict__ k,
                                                 const float* __restrict__ wq,
                                                 const float* __restrict__ wkv,
                                                 const float* __restrict__ wout,
                                                 bf16* __restrict__ dst) {
  const size_t i = ((size_t)blockIdx.x * 256 + threadIdx.x) * 8;
  const float* src; size_t off; float sc = 1.0f;
  if (i < 8388608)        { src = q;    off = i; sc = 0.18033688f; }
  else if (i < 16777216)  { src = k;    off = i - 8388608; }
  else if (i < 17825792)  { src = wq;   off = i - 16777216; }
  else if (i < 19922944)  { src = wkv;  off = i - 17825792; }
  else                    { src = wout; off = i - 19922944; }
  const f32x4 a = *reinterpret_cast<const f32x4*>(src + off);
  const f32x4 b = *reinterpret_cast<const f32x4*>(src + off + 4);
  bf16x8 o;
  o[0] = (bf16)(a.x * sc); o[1] = (bf16)(a.y * sc);
  o[2] = (bf16)(a.z * sc); o[3] = (bf16)(a.w * sc);
  o[4] = (bf16)(b.x * sc); o[5] = (bf16)(b.y * sc);
  o[6] = (bf16)(b.z * sc); o[7] = (bf16)(b.w * sc);
  *reinterpret_cast<bf16x8*>(dst + i) = o;
}

// ============================================================================
// m97-structure bf16 GEMM (R4/R9/R12-exact): 128x128 tile, BK=32, 4 waves 2x2,
// global_load_lds(16B) staging, 2-barrier K-loop, XCD swizzle.
// MODE 0 (fused proj, 1536 blocks): by 0-7: q2@Wq -> qh | 8-15: k2@Wkv lo -> kh
//        | 16-23: k2@Wkv hi -> vh     (HEAD-major [bh][l][d], 32B segments)
// MODE 2 (out proj, 512 blocks): ctx @ Wout -> f32 out (token-major, NT)
// ============================================================================
template <int MODE>
__global__ __launch_bounds__(256) void k_gemm(const bf16* __restrict__ Aq,
                                              const bf16* __restrict__ Ak,
                                              const bf16* __restrict__ Wq,
                                              const bf16* __restrict__ Wkv,
                                              bf16* __restrict__ qh,
                                              bf16* __restrict__ kh,
                                              bf16* __restrict__ vh,
                                              float* __restrict__ o_f) {
  __shared__ bf16 As[128 * 32];
  __shared__ bf16 Bs[128 * 32];

  const int tid  = threadIdx.x;
  const int lane = tid & 63, wave = tid >> 6;
  const int wm = wave & 1, wn = wave >> 1;

  const int cpx = gridDim.x >> 3;
  const int logical = (blockIdx.x & 7) * cpx + (blockIdx.x >> 3);
  const int bx = logical & 63, by = logical >> 6;
  const int m0 = bx * 128;

  const bf16* Ap;
  const bf16* Wp;
  bf16* Op = nullptr;
  if constexpr (MODE == 0) {
    if (by < 8)       { Ap = Aq; Wp = Wq  + (size_t)by * 131072;        Op = qh; }
    else if (by < 16) { Ap = Ak; Wp = Wkv + (size_t)(by - 8) * 131072;  Op = kh; }
    else              { Ap = Ak; Wp = Wkv + 1048576 + (size_t)(by - 16) * 131072; Op = vh; }
  } else {
    Ap = Aq; Wp = Wq + (size_t)by * 131072;
  }
  const int col0 = (by & 7) * 128;

  const int fr = lane & 15, fo = (lane >> 4) * 8;

  f32x4 acc[4][4] = {};

  const int srow = lane >> 2;          // 0..15
  const int scol = (lane & 3) * 8;     // elems
  const bf16* ga = Ap + (size_t)(m0 + wave * 32 + srow) * Ec + scol;
  const bf16* gb = Wp + (size_t)(wave * 32 + srow) * Ec + scol;
  bf16* lA = As + wave * 1024;
  bf16* lB = Bs + wave * 1024;

  for (int k0 = 0; k0 < Ec; k0 += 32) {
    gload_lds16(ga + k0, lA);
    gload_lds16(ga + k0 + 16 * Ec, lA + 512);
    gload_lds16(gb + k0, lB);
    gload_lds16(gb + k0 + 16 * Ec, lB + 512);
    __syncthreads();

    bf16x8 a[4], b[4];
#pragma unroll
    for (int i = 0; i < 4; ++i) {
      a[i] = *reinterpret_cast<const bf16x8*>(As + (wm * 64 + i * 16 + fr) * 32 + fo);
      b[i] = *reinterpret_cast<const bf16x8*>(Bs + (wn * 64 + i * 16 + fr) * 32 + fo);
    }
#pragma unroll
    for (int i = 0; i < 4; ++i)
#pragma unroll
      for (int j = 0; j < 4; ++j) acc[i][j] = MFMA16(a[i], b[j], acc[i][j]);
    __syncthreads();
  }

  const int rb = (lane >> 4) * 4;
#pragma unroll
  for (int i = 0; i < 4; ++i) {
#pragma unroll
    for (int j = 0; j < 4; ++j) {
      const int col = col0 + wn * 64 + j * 16 + fr;
#pragma unroll
      for (int r = 0; r < 4; ++r) {
        const int tok = m0 + wm * 64 + i * 16 + rb + r;
        const float val = acc[i][j][r];
        if constexpr (MODE == 0) {
          const int lq = tok >> 3, bb = tok & 7;
          const int h = col >> 6, dd = col & 63;
          Op[(((size_t)(bb * Hc + h)) * LQc + lq) * Dc + dd] = (bf16)val;
        } else {
          __builtin_nontemporal_store(val, o_f + (size_t)tok * Ec + col);
        }
      }
    }
  }
}

// ============================================================================
// Transpose Vh[bh][lk][64] -> VhT[bh][64][lk], 64x64 LDS tiles (R4/R9-exact)
// ============================================================================
__global__ __launch_bounds__(256) void k_vtrans(const bf16* __restrict__ Vh,
                                                bf16* __restrict__ VhT) {
  __shared__ bf16 tile[64][72];
  const int bh = blockIdx.y;
  const int l0 = blockIdx.x * 64;
  const int r = threadIdx.x >> 3, c = (threadIdx.x & 7) * 8;
#pragma unroll
  for (int rr = 0; rr < 2; ++rr) {
    const int row = rr * 32 + r;
    *reinterpret_cast<bf16x8*>(&tile[row][c]) =
        *reinterpret_cast<const bf16x8*>(Vh + ((size_t)bh * LKc + l0 + row) * Dc + c);
  }
  __syncthreads();
#pragma unroll
  for (int rr = 0; rr < 2; ++rr) {
    const int d = rr * 32 + r;
    bf16x8 o;
#pragma unroll
    for (int j = 0; j < 8; ++j) o[j] = tile[c + j][d];
    *reinterpret_cast<bf16x8*>(VhT + ((size_t)bh * Dc + d) * LKc + l0 + c) = o;
  }
}

// ============================================================================
// Attention (R14 structure + exp2-domain + single-barrier sum): block =
// (b,h) x 32 q-rows, 4 waves. Swapped QK^T -> exp2(f32) -> e in LDS + sums
// -> psum -> ONE barrier; each wave computes 1/sum locally (broadcast psum
// reads). Prob-write per wave (8 rows, 1KB/instr NT stores); wave-level
// write/PV anti-phase keyed on ((wave>>1)^parity).
// ============================================================================
__global__ __launch_bounds__(256) void k_attn(const bf16* __restrict__ Qh,
                                              const bf16* __restrict__ Kh,
                                              const bf16* __restrict__ VhT,
                                              const int* __restrict__ mask,
                                              float* __restrict__ attn_out,
                                              bf16* __restrict__ ctx_out) {
  __shared__ bf16 sP[32][1032];
  __shared__ float smask[1024];
  __shared__ float psum[4][32];

  const int tid = threadIdx.x;
  const int lane = tid & 63, wave = tid >> 6;
  const int parity = (blockIdx.x >> 9) & 1;     // generation parity

  int flat = blockIdx.x;                 // 4096 blocks
  flat = (flat & 7) * 512 + (flat >> 3); // XCD swizzle: b == XCD
  const int bh = flat >> 5;
  const int q0 = (flat & 31) * 32;
  const int b = bh >> 4, h = bh & 15;
  const int fr = lane & 15, fo = (lane >> 4) * 8, rb = (lane >> 4) * 4;

#pragma unroll
  for (int c = tid; c < 1024; c += 256)
    smask[c] = mask[b * LKc + c] ? -1e9f : 0.0f;

  // Q fragments from head-major Qh (pre-scaled by 0.125*log2e in convert)
  bf16x8 qf[2][2];
  const bf16* Qb = Qh + ((size_t)bh * LQc + q0) * Dc;
#pragma unroll
  for (int m = 0; m < 2; ++m)
#pragma unroll
    for (int kc = 0; kc < 2; ++kc)
      qf[m][kc] = *reinterpret_cast<const bf16x8*>(Qb + (size_t)(m * 16 + fr) * Dc + kc * 32 + fo);
  __syncthreads();  // smask ready

  // ---- swapped QK^T: D[k][q]; lane holds q=fr (m0) / 16+fr (m1), k=n+rb+r ----
  const bf16* Kb = Kh + (size_t)bh * LKc * Dc;
  float s0 = 0.f, s1 = 0.f;
#pragma unroll 4
  for (int t = 0; t < 16; ++t) {
    const int n = (wave * 16 + t) * 16;
    const bf16* kp = Kb + (size_t)(n + fr) * Dc + fo;
    const bf16x8 kf0 = *reinterpret_cast<const bf16x8*>(kp);
    const bf16x8 kf1 = *reinterpret_cast<const bf16x8*>(kp + 32);
    f32x4 c0 = {}, c1 = {};
    c0 = MFMA16(kf0, qf[0][0], c0);
    c0 = MFMA16(kf1, qf[0][1], c0);
    c1 = MFMA16(kf0, qf[1][0], c1);
    c1 = MFMA16(kf1, qf[1][1], c1);
    const int kb = n + rb;
    const f32x4 madd = *reinterpret_cast<const f32x4*>(&smask[kb]);
    bf16x4 p0, p1;
#pragma unroll
    for (int r = 0; r < 4; ++r) {
      const float e0 = EXP2F(c0[r] + madd[r]);
      const float e1 = EXP2F(c1[r] + madd[r]);
      s0 += e0; s1 += e1;
      p0[r] = (bf16)e0; p1[r] = (bf16)e1;
    }
    *reinterpret_cast<bf16x4*>(&sP[fr][kb])      = p0;
    *reinterpret_cast<bf16x4*>(&sP[16 + fr][kb]) = p1;
  }
  // reduce across the 4 rb-groups (lanes 16 apart, same fr)
  s0 += __shfl_xor(s0, 16, 64); s0 += __shfl_xor(s0, 32, 64);
  s1 += __shfl_xor(s1, 16, 64); s1 += __shfl_xor(s1, 32, 64);
  if (lane < 16) {
    psum[wave][fr]      = s0;
    psum[wave][16 + fr] = s1;
  }
  __syncthreads();  // psum + sP complete; waves proceed independently now

  float* ap = attn_out + ((size_t)bh * LQc + q0) * LKc;
  const bf16* Vb = VhT + ((size_t)bh * Dc + wave * 16 + fr) * LKc;
  f32x4 cacc0 = {}, cacc1 = {};

  const int wrbase = wave * 8;                      // this wave's 8 write rows
  const bool write_first = (((wave >> 1) & 1) ^ parity) == 0;

  if (write_first) {
    // ---- this wave: prob write (its 8 rows) then PV ----
#pragma unroll 2
    for (int rr = 0; rr < 8; ++rr) {
      const int r = wrbase + rr;
      const float rs = 1.0f / (psum[0][r] + psum[1][r] + psum[2][r] + psum[3][r]);
#pragma unroll
      for (int ch = 0; ch < 4; ++ch) {
        const bf16x4 v = *reinterpret_cast<const bf16x4*>(&sP[r][ch * 256 + lane * 4]);
        f32x4 p;
        p.x = (float)v.x * rs; p.y = (float)v.y * rs;
        p.z = (float)v.z * rs; p.w = (float)v.w * rs;
        __builtin_nontemporal_store(p,
            reinterpret_cast<f32x4*>(ap + (size_t)r * LKc + ch * 256 + lane * 4));
      }
    }
#pragma unroll 4
    for (int kc = 0; kc < 1024; kc += 32) {
      const bf16x8 vf  = *reinterpret_cast<const bf16x8*>(Vb + kc + fo);
      const bf16x8 pa0 = *reinterpret_cast<const bf16x8*>(&sP[fr][kc + fo]);
      const bf16x8 pa1 = *reinterpret_cast<const bf16x8*>(&sP[16 + fr][kc + fo]);
      cacc0 = MFMA16(pa0, vf, cacc0);
      cacc1 = MFMA16(pa1, vf, cacc1);
    }
  } else {
    // ---- this wave: PV then prob write (its 8 rows) ----
#pragma unroll 4
    for (int kc = 0; kc < 1024; kc += 32) {
      const bf16x8 vf  = *reinterpret_cast<const bf16x8*>(Vb + kc + fo);
      const bf16x8 pa0 = *reinterpret_cast<const bf16x8*>(&sP[fr][kc + fo]);
      const bf16x8 pa1 = *reinterpret_cast<const bf16x8*>(&sP[16 + fr][kc + fo]);
      cacc0 = MFMA16(pa0, vf, cacc0);
      cacc1 = MFMA16(pa1, vf, cacc1);
    }
#pragma unroll 2
    for (int rr = 0; rr < 8; ++rr) {
      const int r = wrbase + rr;
      const float rs = 1.0f / (psum[0][r] + psum[1][r] + psum[2][r] + psum[3][r]);
#pragma unroll
      for (int ch = 0; ch < 4; ++ch) {
        const bf16x4 v = *reinterpret_cast<const bf16x4*>(&sP[r][ch * 256 + lane * 4]);
        f32x4 p;
        p.x = (float)v.x * rs; p.y = (float)v.y * rs;
        p.z = (float)v.z * rs; p.w = (float)v.w * rs;
        __builtin_nontemporal_store(p,
            reinterpret_cast<f32x4*>(ap + (size_t)r * LKc + ch * 256 + lane * 4));
      }
    }
  }

  const int e = h * Dc + wave * 16 + fr;
#pragma unroll
  for (int r = 0; r < 4; ++r) {
    const int row0 = rb + r, row1 = 16 + rb + r;
    const float rs0 = 1.0f / (psum[0][row0] + psum[1][row0] + psum[2][row0] + psum[3][row0]);
    const float rs1 = 1.0f / (psum[0][row1] + psum[1][row1] + psum[2][row1] + psum[3][row1]);
    ctx_out[((size_t)(q0 + row0) * Bc + b) * Ec + e] = (bf16)(cacc0[r] * rs0);
    ctx_out[((size_t)(q0 + row1) * Bc + b) * Ec + e] = (bf16)(cacc1[r] * rs1);
  }
}

// ============================================================================
extern "C" void kernel_launch(void* const* d_in, const int* in_sizes, int n_in,
                              void* d_out, int out_size, void* d_ws, size_t ws_size,
                              hipStream_t stream) {
  const float* query = (const float*)d_in[0];
  const float* keyx  = (const float*)d_in[1];
  const int*   mask  = (const int*)d_in[2];
  const float* wq    = (const float*)d_in[3];
  const float* wkv   = (const float*)d_in[4];
  const float* wout  = (const float*)d_in[5];

  float* out  = (float*)d_out;                  // (LQ,B,E) flat
  float* attn = out + (size_t)LQc * Bc * Ec;    // (B,H,LQ,LK) flat

  bf16* cvt   = (bf16*)d_ws;
  bf16* q2    = cvt;                    // 8,388,608 (pre-scaled)
  bf16* k2    = q2   + 8388608;         // 8,388,608
  bf16* wqb   = k2   + 8388608;         // 1,048,576
  bf16* wkvb  = wqb  + 1048576;         // 2,097,152
  bf16* woutb = wkvb + 2097152;         // 1,048,576
  bf16* qh    = woutb + 1048576;        // 8,388,608 head-major
  bf16* kh    = qh   + 8388608;         // 8,388,608 head-major
  bf16* vh    = kh   + 8388608;         // 8,388,608 head-major
  bf16* vt    = q2;                     // alias: q2 dead after proj gemm
  bf16* ctx   = k2;                     // alias: k2 dead after proj gemm

  k_convert<<<10240, 256, 0, stream>>>(query, keyx, wq, wkv, wout, cvt);
  k_gemm<0><<<1536, 256, 0, stream>>>(q2, k2, wqb, wkvb, qh, kh, vh, nullptr);
  k_vtrans<<<dim3(16, 128), 256, 0, stream>>>(vh, vt);
  k_attn<<<4096, 256, 0, stream>>>(qh, kh, vt, mask, attn, ctx);
  k_gemm<2><<<512, 256, 0, stream>>>(ctx, nullptr, woutb, nullptr, nullptr, nullptr, nullptr, out);
}

// Round 17
// 292.024 us; speedup vs baseline: 1.0127x; 1.0127x over previous
//
#include <hip/hip_runtime.h>
#include <hip/hip_bf16.h>
#include <cstdint>
#include <cstddef>

// ---- problem constants ----
constexpr int LQc = 1024, LKc = 1024, Bc = 8, Ec = 1024, Hc = 16, Dc = 64;

typedef __bf16 bf16;
typedef __bf16 bf16x4 __attribute__((ext_vector_type(4)));
typedef __bf16 bf16x8 __attribute__((ext_vector_type(8)));
typedef float  f32x4  __attribute__((ext_vector_type(4)));

#define MFMA16(a, b, c) __builtin_amdgcn_mfma_f32_16x16x32_bf16((a), (b), (c), 0, 0, 0)
#define EXP2F(x) __builtin_amdgcn_exp2f(x)

__device__ __forceinline__ void gload_lds16(const bf16* g, bf16* l) {
  __builtin_amdgcn_global_load_lds((const __attribute__((address_space(1))) void*)g,
                                   (__attribute__((address_space(3))) void*)l, 16, 0, 0);
}

// ============================================================================
// Convert f32 inputs -> bf16. query scaled by 0.125*log2(e).
// ============================================================================
__global__ __launch_bounds__(256) void k_convert(const float* __restrict__ q,
                                                 const float* __restrict__ k,
                                                 const float* __restrict__ wq,
                                                 const float* __restrict__ wkv,
                                                 const float* __restrict__ wout,
                                                 bf16* __restrict__ dst) {
  const size_t i = ((size_t)blockIdx.x * 256 + threadIdx.x) * 8;
  const float* src; size_t off; float sc = 1.0f;
  if (i < 8388608)        { src = q;    off = i; sc = 0.18033688f; }
  else if (i < 16777216)  { src = k;    off = i - 8388608; }
  else if (i < 17825792)  { src = wq;   off = i - 16777216; }
  else if (i < 19922944)  { src = wkv;  off = i - 17825792; }
  else                    { src = wout; off = i - 19922944; }
  const f32x4 a = *reinterpret_cast<const f32x4*>(src + off);
  const f32x4 b = *reinterpret_cast<const f32x4*>(src + off + 4);
  bf16x8 o;
  o[0] = (bf16)(a.x * sc); o[1] = (bf16)(a.y * sc);
  o[2] = (bf16)(a.z * sc); o[3] = (bf16)(a.w * sc);
  o[4] = (bf16)(b.x * sc); o[5] = (bf16)(b.y * sc);
  o[6] = (bf16)(b.z * sc); o[7] = (bf16)(b.w * sc);
  *reinterpret_cast<bf16x8*>(dst + i) = o;
}

// ============================================================================
// 8-wave 256x256 group-pipelined proj GEMM (T3+T4 mechanism, BK=64):
// 384 blocks (32 bx x 12 by), 512 thr = 8 waves (2M x 4N), wave tile 128x64.
// LDS 128KB: A/B x 2 K-tile dbufs x [2 halves][128 rows][64] bf16,
// XOR-chunk swizzle (chunk ^= row&7) via pre-swizzled global source + same
// XOR on ds_read (conflict-free b128). Per group (one K-tile, 64 MFMA/wave):
// issue ALL 8 next-tile gload_lds -> vmcnt(8) (oldest 8 = current tile
// retired; new 8 fly across the group) -> barrier -> B-frags + 4 quadrants
// {A-frags, 16 MFMA} -> barrier. No vmcnt(0) drains in the main loop.
// by 0-3: q2@Wq slab -> qh | 4-7: k2@Wkv lo -> kh | 8-11: k2@Wkv hi -> vh
// (HEAD-major [bh][l][d]).
// ============================================================================
__global__ __launch_bounds__(512, 2) void k_gemm8(const bf16* __restrict__ Aq,
                                                  const bf16* __restrict__ Ak,
                                                  const bf16* __restrict__ Wq,
                                                  const bf16* __restrict__ Wkv,
                                                  bf16* __restrict__ qh,
                                                  bf16* __restrict__ kh,
                                                  bf16* __restrict__ vh) {
  __shared__ bf16 lds[65536];  // [A: 2x16384][B at +32768: 2x16384]

  const int tid = threadIdx.x, lane = tid & 63, wave = tid >> 6;  // 0..7
  const int wm = wave >> 2, wn = wave & 3;                        // 2M x 4N
  const int fr = lane & 15, q4 = lane >> 4;

  // XCD swizzle (384 % 8 == 0)
  const int logical = (blockIdx.x & 7) * 48 + (blockIdx.x >> 3);
  const int bx = logical & 31, by = logical >> 5;
  const int m0 = bx * 256;

  const bf16* Ap = (by < 4) ? Aq : Ak;
  const bf16* Wp;
  bf16* Op;
  if (by < 4)      { Wp = Wq  + (size_t)by * 262144;              Op = qh; }
  else if (by < 8) { Wp = Wkv + (size_t)(by - 4) * 262144;        Op = kh; }
  else             { Wp = Wkv + 1048576 + (size_t)(by - 8) * 262144; Op = vh; }

  // staging: wave stages rows [w*16, w*16+16) of each 128-row half;
  // per gload: 8 rows, lane -> row=(l>>3), chunk=(l&7) pre-swizzled by row&7
  const int srow = lane >> 3;                                // 0..7
  const int scol = ((lane & 7) ^ (srow & 7)) * 8;            // pre-swizzled
  const bf16* gA0 = Ap + (size_t)(m0 + wave * 16 + srow) * 1024 + scol;
  const bf16* gW0 = Wp + (size_t)(wave * 16 + srow) * 1024 + scol;

#define STAGE_A(nd, kt, h) do {                                        \
    const bf16* s_ = gA0 + (size_t)(h) * 131072 + (kt) * 64;           \
    bf16* d_ = lds + (nd) * 16384 + (h) * 8192 + wave * 1024;          \
    gload_lds16(s_, d_); gload_lds16(s_ + 8192, d_ + 512);             \
  } while (0)
#define STAGE_B(nd, kt, h) do {                                        \
    const bf16* s_ = gW0 + (size_t)(h) * 131072 + (kt) * 64;           \
    bf16* d_ = lds + 32768 + (nd) * 16384 + (h) * 8192 + wave * 1024;  \
    gload_lds16(s_, d_); gload_lds16(s_ + 8192, d_ + 512);             \
  } while (0)

  // read-side swizzled chunk offsets (elems): chunk = (kk*4+q4) ^ (fr&7)
  const int cs0 = ((q4) ^ (fr & 7)) * 8;      // kk=0
  // kk=1 chunk offset = cs0 ^ 64 elems? (4+q4)^f = 4 ^ (q4^f) -> +(4<<3)=32 elems XOR
  const int cs1 = cs0 ^ 32;

  f32x4 acc[8][4] = {};
  bf16x8 bfr[4][2];

  // prologue: K-tile 0 -> dbuf0
  STAGE_A(0, 0, 0); STAGE_A(0, 0, 1); STAGE_B(0, 0, 0); STAGE_B(0, 0, 1);

#define COMPUTE_GROUP(d)                                                      \
  {                                                                           \
    const bf16* lb = lds + 32768 + (d) * 16384 + (wn >> 1) * 8192 +           \
                     (wn & 1) * 4096;                                         \
    _Pragma("unroll") for (int n = 0; n < 4; ++n) {                           \
      bfr[n][0] = *(const bf16x8*)(lb + (n * 16 + fr) * 64 + cs0);            \
      bfr[n][1] = *(const bf16x8*)(lb + (n * 16 + fr) * 64 + cs1);            \
    }                                                                         \
    const bf16* la = lds + (d) * 16384 + wm * 8192 + fr * 64;                 \
    _Pragma("unroll") for (int qq = 0; qq < 4; ++qq) {                        \
      bf16x8 af[2][2];                                                        \
      _Pragma("unroll") for (int mm = 0; mm < 2; ++mm) {                      \
        const int m_ = qq * 2 + mm;                                           \
        af[mm][0] = *(const bf16x8*)(la + m_ * 1024 + cs0);                   \
        af[mm][1] = *(const bf16x8*)(la + m_ * 1024 + cs1);                   \
      }                                                                       \
      _Pragma("unroll") for (int mm = 0; mm < 2; ++mm)                        \
        _Pragma("unroll") for (int n = 0; n < 4; ++n) {                       \
          acc[qq * 2 + mm][n] = MFMA16(af[mm][0], bfr[n][0], acc[qq * 2 + mm][n]); \
          acc[qq * 2 + mm][n] = MFMA16(af[mm][1], bfr[n][1], acc[qq * 2 + mm][n]); \
        }                                                                     \
    }                                                                         \
  }

#pragma unroll 1
  for (int g = 0; g < 15; ++g) {
    const int d = g & 1, nd = d ^ 1;
    STAGE_A(nd, g + 1, 0); STAGE_A(nd, g + 1, 1);
    STAGE_B(nd, g + 1, 0); STAGE_B(nd, g + 1, 1);
    asm volatile("s_waitcnt vmcnt(8)" ::: "memory");  // K-tile g retired; 8 fly
    asm volatile("s_barrier" ::: "memory");           // all waves' slices ready
    COMPUTE_GROUP(d);
    asm volatile("s_barrier" ::: "memory");           // dbuf d reads done
  }
  asm volatile("s_waitcnt vmcnt(0)" ::: "memory");
  asm volatile("s_barrier" ::: "memory");
  COMPUTE_GROUP(1);

  // epilogue: head-major [b][h][l][d]; C/D: col=fr, row=q4*4+r
  const int rb = q4 * 4;
#pragma unroll
  for (int m = 0; m < 8; ++m) {
#pragma unroll
    for (int n = 0; n < 4; ++n) {
      const int f = (by & 3) * 256 + wn * 64 + n * 16 + fr;
      const int h = f >> 6, dd = f & 63;
#pragma unroll
      for (int r = 0; r < 4; ++r) {
        const int tok = m0 + wm * 128 + m * 16 + rb + r;
        const int lq = tok >> 3, bb = tok & 7;
        Op[(((size_t)(bb * Hc + h)) * LQc + lq) * Dc + dd] = (bf16)acc[m][n][r];
      }
    }
  }
#undef STAGE_A
#undef STAGE_B
#undef COMPUTE_GROUP
}

// ============================================================================
// m97-structure bf16 GEMM (proven) — MODE 2 out-proj only:
// 512 blocks, ctx @ Wout -> f32 out (token-major, NT stores).
// ============================================================================
template <int MODE>
__global__ __launch_bounds__(256) void k_gemm(const bf16* __restrict__ Aq,
                                              const bf16* __restrict__ Wq,
                                              float* __restrict__ o_f) {
  __shared__ bf16 As[128 * 32];
  __shared__ bf16 Bs[128 * 32];

  const int tid  = threadIdx.x;
  const int lane = tid & 63, wave = tid >> 6;
  const int wm = wave & 1, wn = wave >> 1;

  const int cpx = gridDim.x >> 3;
  const int logical = (blockIdx.x & 7) * cpx + (blockIdx.x >> 3);
  const int bx = logical & 63, by = logical >> 6;
  const int m0 = bx * 128;

  const bf16* Ap = Aq;
  const bf16* Wp = Wq + (size_t)by * 131072;
  const int col0 = (by & 7) * 128;

  const int fr = lane & 15, fo = (lane >> 4) * 8;

  f32x4 acc[4][4] = {};

  const int srow = lane >> 2;
  const int scol = (lane & 3) * 8;
  const bf16* ga = Ap + (size_t)(m0 + wave * 32 + srow) * Ec + scol;
  const bf16* gb = Wp + (size_t)(wave * 32 + srow) * Ec + scol;
  bf16* lA = As + wave * 1024;
  bf16* lB = Bs + wave * 1024;

  for (int k0 = 0; k0 < Ec; k0 += 32) {
    gload_lds16(ga + k0, lA);
    gload_lds16(ga + k0 + 16 * Ec, lA + 512);
    gload_lds16(gb + k0, lB);
    gload_lds16(gb + k0 + 16 * Ec, lB + 512);
    __syncthreads();

    bf16x8 a[4], b[4];
#pragma unroll
    for (int i = 0; i < 4; ++i) {
      a[i] = *reinterpret_cast<const bf16x8*>(As + (wm * 64 + i * 16 + fr) * 32 + fo);
      b[i] = *reinterpret_cast<const bf16x8*>(Bs + (wn * 64 + i * 16 + fr) * 32 + fo);
    }
#pragma unroll
    for (int i = 0; i < 4; ++i)
#pragma unroll
      for (int j = 0; j < 4; ++j) acc[i][j] = MFMA16(a[i], b[j], acc[i][j]);
    __syncthreads();
  }

  const int rb = (lane >> 4) * 4;
#pragma unroll
  for (int i = 0; i < 4; ++i) {
#pragma unroll
    for (int j = 0; j < 4; ++j) {
      const int col = col0 + wn * 64 + j * 16 + fr;
#pragma unroll
      for (int r = 0; r < 4; ++r) {
        const int tok = m0 + wm * 64 + i * 16 + rb + r;
        __builtin_nontemporal_store(acc[i][j][r], o_f + (size_t)tok * Ec + col);
      }
    }
  }
}

// ============================================================================
// Transpose Vh[bh][lk][64] -> VhT[bh][64][lk] (proven)
// ============================================================================
__global__ __launch_bounds__(256) void k_vtrans(const bf16* __restrict__ Vh,
                                                bf16* __restrict__ VhT) {
  __shared__ bf16 tile[64][72];
  const int bh = blockIdx.y;
  const int l0 = blockIdx.x * 64;
  const int r = threadIdx.x >> 3, c = (threadIdx.x & 7) * 8;
#pragma unroll
  for (int rr = 0; rr < 2; ++rr) {
    const int row = rr * 32 + r;
    *reinterpret_cast<bf16x8*>(&tile[row][c]) =
        *reinterpret_cast<const bf16x8*>(Vh + ((size_t)bh * LKc + l0 + row) * Dc + c);
  }
  __syncthreads();
#pragma unroll
  for (int rr = 0; rr < 2; ++rr) {
    const int d = rr * 32 + r;
    bf16x8 o;
#pragma unroll
    for (int j = 0; j < 8; ++j) o[j] = tile[c + j][d];
    *reinterpret_cast<bf16x8*>(VhT + ((size_t)bh * Dc + d) * LKc + l0 + c) = o;
  }
}

// ============================================================================
// Attention (R16 champion-equivalent, unchanged)
// ============================================================================
__global__ __launch_bounds__(256) void k_attn(const bf16* __restrict__ Qh,
                                              const bf16* __restrict__ Kh,
                                              const bf16* __restrict__ VhT,
                                              const int* __restrict__ mask,
                                              float* __restrict__ attn_out,
                                              bf16* __restrict__ ctx_out) {
  __shared__ bf16 sP[32][1032];
  __shared__ float smask[1024];
  __shared__ float psum[4][32];

  const int tid = threadIdx.x;
  const int lane = tid & 63, wave = tid >> 6;
  const int parity = (blockIdx.x >> 9) & 1;

  int flat = blockIdx.x;
  flat = (flat & 7) * 512 + (flat >> 3);
  const int bh = flat >> 5;
  const int q0 = (flat & 31) * 32;
  const int b = bh >> 4, h = bh & 15;
  const int fr = lane & 15, fo = (lane >> 4) * 8, rb = (lane >> 4) * 4;

#pragma unroll
  for (int c = tid; c < 1024; c += 256)
    smask[c] = mask[b * LKc + c] ? -1e9f : 0.0f;

  bf16x8 qf[2][2];
  const bf16* Qb = Qh + ((size_t)bh * LQc + q0) * Dc;
#pragma unroll
  for (int m = 0; m < 2; ++m)
#pragma unroll
    for (int kc = 0; kc < 2; ++kc)
      qf[m][kc] = *reinterpret_cast<const bf16x8*>(Qb + (size_t)(m * 16 + fr) * Dc + kc * 32 + fo);
  __syncthreads();

  const bf16* Kb = Kh + (size_t)bh * LKc * Dc;
  float s0 = 0.f, s1 = 0.f;
#pragma unroll 4
  for (int t = 0; t < 16; ++t) {
    const int n = (wave * 16 + t) * 16;
    const bf16* kp = Kb + (size_t)(n + fr) * Dc + fo;
    const bf16x8 kf0 = *reinterpret_cast<const bf16x8*>(kp);
    const bf16x8 kf1 = *reinterpret_cast<const bf16x8*>(kp + 32);
    f32x4 c0 = {}, c1 = {};
    c0 = MFMA16(kf0, qf[0][0], c0);
    c0 = MFMA16(kf1, qf[0][1], c0);
    c1 = MFMA16(kf0, qf[1][0], c1);
    c1 = MFMA16(kf1, qf[1][1], c1);
    const int kb = n + rb;
    const f32x4 madd = *reinterpret_cast<const f32x4*>(&smask[kb]);
    bf16x4 p0, p1;
#pragma unroll
    for (int r = 0; r < 4; ++r) {
      const float e0 = EXP2F(c0[r] + madd[r]);
      const float e1 = EXP2F(c1[r] + madd[r]);
      s0 += e0; s1 += e1;
      p0[r] = (bf16)e0; p1[r] = (bf16)e1;
    }
    *reinterpret_cast<bf16x4*>(&sP[fr][kb])      = p0;
    *reinterpret_cast<bf16x4*>(&sP[16 + fr][kb]) = p1;
  }
  s0 += __shfl_xor(s0, 16, 64); s0 += __shfl_xor(s0, 32, 64);
  s1 += __shfl_xor(s1, 16, 64); s1 += __shfl_xor(s1, 32, 64);
  if (lane < 16) {
    psum[wave][fr]      = s0;
    psum[wave][16 + fr] = s1;
  }
  __syncthreads();

  float* ap = attn_out + ((size_t)bh * LQc + q0) * LKc;
  const bf16* Vb = VhT + ((size_t)bh * Dc + wave * 16 + fr) * LKc;
  f32x4 cacc0 = {}, cacc1 = {};

  const int wrbase = wave * 8;
  const bool write_first = (((wave >> 1) & 1) ^ parity) == 0;

  if (write_first) {
#pragma unroll 2
    for (int rr = 0; rr < 8; ++rr) {
      const int r = wrbase + rr;
      const float rs = 1.0f / (psum[0][r] + psum[1][r] + psum[2][r] + psum[3][r]);
#pragma unroll
      for (int ch = 0; ch < 4; ++ch) {
        const bf16x4 v = *reinterpret_cast<const bf16x4*>(&sP[r][ch * 256 + lane * 4]);
        f32x4 p;
        p.x = (float)v.x * rs; p.y = (float)v.y * rs;
        p.z = (float)v.z * rs; p.w = (float)v.w * rs;
        __builtin_nontemporal_store(p,
            reinterpret_cast<f32x4*>(ap + (size_t)r * LKc + ch * 256 + lane * 4));
      }
    }
#pragma unroll 4
    for (int kc = 0; kc < 1024; kc += 32) {
      const bf16x8 vf  = *reinterpret_cast<const bf16x8*>(Vb + kc + fo);
      const bf16x8 pa0 = *reinterpret_cast<const bf16x8*>(&sP[fr][kc + fo]);
      const bf16x8 pa1 = *reinterpret_cast<const bf16x8*>(&sP[16 + fr][kc + fo]);
      cacc0 = MFMA16(pa0, vf, cacc0);
      cacc1 = MFMA16(pa1, vf, cacc1);
    }
  } else {
#pragma unroll 4
    for (int kc = 0; kc < 1024; kc += 32) {
      const bf16x8 vf  = *reinterpret_cast<const bf16x8*>(Vb + kc + fo);
      const bf16x8 pa0 = *reinterpret_cast<const bf16x8*>(&sP[fr][kc + fo]);
      const bf16x8 pa1 = *reinterpret_cast<const bf16x8*>(&sP[16 + fr][kc + fo]);
      cacc0 = MFMA16(pa0, vf, cacc0);
      cacc1 = MFMA16(pa1, vf, cacc1);
    }
#pragma unroll 2
    for (int rr = 0; rr < 8; ++rr) {
      const int r = wrbase + rr;
      const float rs = 1.0f / (psum[0][r] + psum[1][r] + psum[2][r] + psum[3][r]);
#pragma unroll
      for (int ch = 0; ch < 4; ++ch) {
        const bf16x4 v = *reinterpret_cast<const bf16x4*>(&sP[r][ch * 256 + lane * 4]);
        f32x4 p;
        p.x = (float)v.x * rs; p.y = (float)v.y * rs;
        p.z = (float)v.z * rs; p.w = (float)v.w * rs;
        __builtin_nontemporal_store(p,
            reinterpret_cast<f32x4*>(ap + (size_t)r * LKc + ch * 256 + lane * 4));
      }
    }
  }

  const int e = h * Dc + wave * 16 + fr;
#pragma unroll
  for (int r = 0; r < 4; ++r) {
    const int row0 = rb + r, row1 = 16 + rb + r;
    const float rs0 = 1.0f / (psum[0][row0] + psum[1][row0] + psum[2][row0] + psum[3][row0]);
    const float rs1 = 1.0f / (psum[0][row1] + psum[1][row1] + psum[2][row1] + psum[3][row1]);
    ctx_out[((size_t)(q0 + row0) * Bc + b) * Ec + e] = (bf16)(cacc0[r] * rs0);
    ctx_out[((size_t)(q0 + row1) * Bc + b) * Ec + e] = (bf16)(cacc1[r] * rs1);
  }
}

// ============================================================================
extern "C" void kernel_launch(void* const* d_in, const int* in_sizes, int n_in,
                              void* d_out, int out_size, void* d_ws, size_t ws_size,
                              hipStream_t stream) {
  const float* query = (const float*)d_in[0];
  const float* keyx  = (const float*)d_in[1];
  const int*   mask  = (const int*)d_in[2];
  const float* wq    = (const float*)d_in[3];
  const float* wkv   = (const float*)d_in[4];
  const float* wout  = (const float*)d_in[5];

  float* out  = (float*)d_out;                  // (LQ,B,E) flat
  float* attn = out + (size_t)LQc * Bc * Ec;    // (B,H,LQ,LK) flat

  bf16* cvt   = (bf16*)d_ws;
  bf16* q2    = cvt;                    // 8,388,608 (pre-scaled)
  bf16* k2    = q2   + 8388608;         // 8,388,608
  bf16* wqb   = k2   + 8388608;         // 1,048,576
  bf16* wkvb  = wqb  + 1048576;         // 2,097,152
  bf16* woutb = wkvb + 2097152;         // 1,048,576
  bf16* qh    = woutb + 1048576;        // 8,388,608 head-major
  bf16* kh    = qh   + 8388608;         // 8,388,608 head-major
  bf16* vh    = kh   + 8388608;         // 8,388,608 head-major
  bf16* vt    = q2;                     // alias: q2 dead after proj gemm
  bf16* ctx   = k2;                     // alias: k2 dead after proj gemm

  k_convert<<<10240, 256, 0, stream>>>(query, keyx, wq, wkv, wout, cvt);
  k_gemm8<<<384, 512, 0, stream>>>(q2, k2, wqb, wkvb, qh, kh, vh);
  k_vtrans<<<dim3(16, 128), 256, 0, stream>>>(vh, vt);
  k_attn<<<4096, 256, 0, stream>>>(qh, kh, vt, mask, attn, ctx);
  k_gemm<2><<<512, 256, 0, stream>>>(ctx, woutb, out);
}